// Round 9
// baseline (813.032 us; speedup 1.0000x reference)
//
#include <hip/hip_runtime.h>

#define BB 512
#define SS 256
#define HH 128
#define NC 10
#define PD 136                 // padded bf16 row stride (2-way-free LDS banking)
#define SGSLOT (4 * 16 * PD)   // shorts per staging slot

typedef __attribute__((ext_vector_type(8))) short bfrag;   // 8 bf16 = 4 VGPR
typedef __attribute__((ext_vector_type(4))) float f32x4;   // MFMA accumulator

__device__ __forceinline__ f32x4 MF(bfrag a, bfrag b, f32x4 c) {
    return __builtin_amdgcn_mfma_f32_16x16x32_bf16(a, b, c, 0, 0, 0);
}

// fp32 -> bf16 (RNE) and back, manual (values are tame; no NaN handling)
__device__ __forceinline__ unsigned f2bf(float x) {
    const unsigned u = __float_as_uint(x);
    return (u + 0x7FFFu + ((u >> 16) & 1u)) >> 16;
}
__device__ __forceinline__ float bf2f(unsigned h) {
    return __uint_as_float(h << 16);
}
__device__ __forceinline__ float tanh_fast(float z) {
    const float e = __expf(2.f * z);
    return 1.f - 2.f * __builtin_amdgcn_rcpf(1.f + e);
}
// Barrier without the compiler's vmcnt(0) drain (LDS-visibility only).
__device__ __forceinline__ void barrier_nodrain() {
    asm volatile("s_waitcnt lgkmcnt(0)\n\ts_barrier" ::: "memory");
}

// Build bf16 hi/lo B-fragments from 8 consecutive fp32 weights.
// Packing: elem i at bits 16*(i&1) of dword i/2 — identical byte order to
// a b128 read of 8 consecutive bf16, so A and B use the same k-mapping.
__device__ __forceinline__ void wfrag(const float* wp, bfrag& fh, bfrag& fl) {
    const float4 v0 = *(const float4*)(wp);
    const float4 v1 = *(const float4*)(wp + 4);
    const float e[8] = {v0.x, v0.y, v0.z, v0.w, v1.x, v1.y, v1.z, v1.w};
    unsigned h[8], l[8];
    #pragma unroll
    for (int i = 0; i < 8; ++i) {
        h[i] = f2bf(e[i]);
        l[i] = f2bf(e[i] - bf2f(h[i]));
    }
    const uint4 uh = make_uint4(h[0] | (h[1] << 16), h[2] | (h[3] << 16),
                                h[4] | (h[5] << 16), h[6] | (h[7] << 16));
    const uint4 ul = make_uint4(l[0] | (l[1] << 16), l[2] | (l[3] << 16),
                                l[4] | (l[5] << 16), l[6] | (l[7] << 16));
    fh = __builtin_bit_cast(bfrag, uh);
    fl = __builtin_bit_cast(bfrag, ul);
}

// =====================================================================
// proj_k: xw0[m][j] = sum_d x[m][d] * W_ih0[j][d]  (bias-free), written
// as SPLIT bf16 (hi, lo) so the scan stages it directly into MFMA
// A-fragment form. Layer 0 only (K=28).
// =====================================================================
template<int K>
__global__ __launch_bounds__(256, 1)
void proj_k(const float* __restrict__ A, const float* __restrict__ W,
            unsigned short* __restrict__ out_hi, unsigned short* __restrict__ out_lo)
{
    constexpr int AS = ((K + 31) / 32) * 32 + 4;
    constexpr int KQ = K / 4;
    constexpr int KCW = (K < 32) ? K : 32;
    constexpr int WQ = KCW / 4;
    const int tid = threadIdx.x;
    const int tx = tid & 15;
    const int ty = tid >> 4;
    const size_t m0 = (size_t)blockIdx.x * 64;

    __shared__ float Arm[64 * AS];
    __shared__ float Wst[128 * 36];

    for (int idx = tid; idx < 64 * KQ; idx += 256) {
        const int row = idx / KQ, kq = idx % KQ;
        const float4 v = *(const float4*)(A + (m0 + row) * K + 4 * kq);
        *(float4*)(&Arm[row * AS + 4 * kq]) = v;
    }

    float acc[4][8];
    #pragma unroll
    for (int c = 0; c < 8; ++c)
        #pragma unroll
        for (int r = 0; r < 4; ++r) acc[r][c] = 0.f;

    #pragma unroll 1
    for (int kc = 0; kc < K; kc += KCW) {
        __syncthreads();
        for (int idx = tid; idx < 128 * WQ; idx += 256) {
            const int col = idx / WQ, q = idx % WQ;
            const float4 v = *(const float4*)(W + (size_t)col * K + kc + 4 * q);
            *(float4*)(&Wst[col * 36 + 4 * q]) = v;
        }
        __syncthreads();
        #pragma unroll 2
        for (int q = 0; q < WQ; ++q) {
            float4 av[4];
            #pragma unroll
            for (int r = 0; r < 4; ++r)
                av[r] = *(const float4*)(&Arm[(ty + 16 * r) * AS + kc + 4 * q]);
            #pragma unroll
            for (int c = 0; c < 8; ++c) {
                const float4 wv = *(const float4*)(&Wst[(tx + 16 * c) * 36 + 4 * q]);
                #pragma unroll
                for (int r = 0; r < 4; ++r)
                    acc[r][c] += av[r].x * wv.x + av[r].y * wv.y
                               + av[r].z * wv.z + av[r].w * wv.w;
            }
        }
    }

    #pragma unroll
    for (int r = 0; r < 4; ++r)
        #pragma unroll
        for (int c = 0; c < 8; ++c) {
            const float v = acc[r][c];
            const unsigned h16 = f2bf(v);
            const unsigned l16 = f2bf(v - bf2f(h16));
            const size_t o = (m0 + ty + 16 * r) * HH + tx + 16 * c;
            out_hi[o] = (unsigned short)h16;
            out_lo[o] = (unsigned short)l16;
        }
}

// =====================================================================
// scan_mfma<PAIR>: TWO stacked layers, wavefront skew 1, 16 batches per
// block on the MATRIX pipe. Per step each layer is one GEMM
//   D[16 x 128] = A[16 x K] @ B[K x 128]   (K=128 for layer0, else 256
//   combined-K: A = [x-half ; own h(s-1)]), computed as split-bf16
//   (hi+lo, 3 MFMA products, lo*lo dropped ~2^-18) with fp32 C accum.
// 512 threads = 8 waves: waves 0-3 layer A (2 N-tiles each), 4-7 layer
// B. Weights pre-split into B-fragments at init (MFMA reads AGPRs
// natively -> the R7/R8 AGPR-copy tax disappears). h state in LDS as
// bf16 hi/lo [2-slot dbuf][16][PD]; h(s) in slot s&1.
//   PAIR=0: A = layer0 (K=128 + staged xw0 as C-init);
//           B = layer1 (K=256), writes split h1 to global dst.
//   PAIR=1: A = layer2 (K=256, x-half = staged h1); B = layer3 (K=256),
//           final h3 -> hfin (fp32).
// Staging: 4-step chunks of (src_hi, src_lo), double-buffered; loads
// issued at T%4==0, LDS-written at T%4==2 (HBM latency hidden under 2
// steps). In-place safe (PAIR0): row R staged at T=4*(R/4)-4, h1 write
// of row R at T=R+1.
// =====================================================================
template<int PAIR>
__global__ __attribute__((amdgpu_flat_work_group_size(512, 512),
                          amdgpu_waves_per_eu(2, 2)))
void scan_mfma(const unsigned short* src_hi, const unsigned short* src_lo,
               unsigned short* dst_hi, unsigned short* dst_lo,
               float* __restrict__ hfin,
               const float* __restrict__ wAx, const float* __restrict__ wAy,
               const float* __restrict__ wBx, const float* __restrict__ wBy,
               const float* __restrict__ bA_ih, const float* __restrict__ bA_hh,
               const float* __restrict__ bB_ih, const float* __restrict__ bB_hh)
{
    const int tid = threadIdx.x;
    const int l  = tid & 63;
    const int wv = tid >> 6;
    const int la = wv >> 2;          // 0 = layer A, 1 = layer B
    const int wq = wv & 3;           // tile-pair index within layer
    const int g  = l >> 4;           // k-subgroup / M-row group
    const int q  = l & 15;           // A: M-row ; B: N-col ; C: N-col
    const int b0 = blockIdx.x * 16;
    const int cn0 = 32 * wq + q, cn1 = cn0 + 16;   // this wave's output cols
    constexpr int KCA = (PAIR == 0) ? 4 : 8;       // layer A K-chunks

    const float* bih = la ? bB_ih : bA_ih;
    const float* bhh = la ? bB_hh : bA_hh;
    const float bias0 = bih[cn0] + bhh[cn0];
    const float bias1 = bih[cn1] + bhh[cn1];

    // B-fragments (weights), split hi/lo: B[k][n] = W[n][k].
    // chunk c<4: x-matrix, k=32c+8g ; c>=4: y-matrix, k=32(c-4)+8g.
    const float* wx = la ? wBx : wAx;
    const float* wy = la ? wBy : wAy;
    bfrag bh[2][8], bl[2][8];
#define LOADW(c)                                                              \
    {                                                                         \
        const float* pm = ((c) < 4) ? wx : wy;                                \
        const int ko = ((c) & 3) * 32 + 8 * g;                                \
        wfrag(pm + (size_t)cn0 * HH + ko, bh[0][(c)], bl[0][(c)]);            \
        wfrag(pm + (size_t)cn1 * HH + ko, bh[1][(c)], bl[1][(c)]);            \
    }
    if (la == 0) {
        #pragma unroll
        for (int c = 0; c < KCA; ++c) LOADW(c);
    } else {
        #pragma unroll
        for (int c = 0; c < 8; ++c) LOADW(c);
    }
#undef LOADW

    // LDS: h dbuf (hi/lo per layer) + staging dbuf (hi/lo)
    __shared__ __align__(16) unsigned short hAh[2][16][PD], hAl[2][16][PD];
    __shared__ __align__(16) unsigned short hBh[2][16][PD], hBl[2][16][PD];
    __shared__ __align__(16) unsigned short sgh[2][4][16][PD], sgl[2][4][16][PD];

    for (int i = tid; i < 2 * 16 * PD; i += 512) {
        ((unsigned short*)hAh)[i] = 0; ((unsigned short*)hAl)[i] = 0;
        ((unsigned short*)hBh)[i] = 0; ((unsigned short*)hBl)[i] = 0;
    }

    // staging decomposition: idx = tid + 512k -> (arr, s, m, k8); loop-invariant
#define STG_SETUP(k)                                                          \
    const int idx##k = tid + 512 * (k);                                       \
    const int arr##k = idx##k >> 10;                                          \
    const int s##k = (idx##k >> 8) & 3;                                       \
    const int m##k = (idx##k >> 4) & 15;                                      \
    const int k8##k = idx##k & 15;                                            \
    const unsigned short* sp##k = (arr##k ? src_lo : src_hi)                  \
        + ((size_t)(b0 + m##k) * SS + s##k) * HH + 8 * k8##k;                 \
    unsigned short* dp##k = arr##k ? &sgl[0][s##k][m##k][8 * k8##k]           \
                                   : &sgh[0][s##k][m##k][8 * k8##k];
    STG_SETUP(0) STG_SETUP(1) STG_SETUP(2) STG_SETUP(3)
#undef STG_SETUP

    // prologue: stage chunk 0 (rows 0..3) into slot 0
    *(uint4*)dp0 = *(const uint4*)sp0;
    *(uint4*)dp1 = *(const uint4*)sp1;
    *(uint4*)dp2 = *(const uint4*)sp2;
    *(uint4*)dp3 = *(const uint4*)sp3;
    __syncthreads();

    uint4 p0, p1, p2, p3;
    for (int T = 0; T <= SS; ++T) {
        const int ph = T & 3, cb = (T >> 2) & 1;

        // staging issue (rows T+4..T+7); held in regs until ph==2
        if (ph == 0 && T + 4 < SS) {
            p0 = *(const uint4*)(sp0 + (size_t)(T + 4) * HH);
            p1 = *(const uint4*)(sp1 + (size_t)(T + 4) * HH);
            p2 = *(const uint4*)(sp2 + (size_t)(T + 4) * HH);
            p3 = *(const uint4*)(sp3 + (size_t)(T + 4) * HH);
        }

        if (la == 0) {
            // ---- layer A computes h_A(T): reads h_A(T-1) slot T^1, writes slot T ----
            if (T < SS) {
                const int rs = (T ^ 1) & 1, ws = T & 1;
                f32x4 c0, c1;
                if (PAIR == 0) {   // C-init = xw0 + bias (staged split-bf16)
                    #pragma unroll
                    for (int j = 0; j < 4; ++j) {
                        const int m = 4 * g + j;
                        c0[j] = bias0 + bf2f(sgh[cb][ph][m][cn0]) + bf2f(sgl[cb][ph][m][cn0]);
                        c1[j] = bias1 + bf2f(sgh[cb][ph][m][cn1]) + bf2f(sgl[cb][ph][m][cn1]);
                    }
                } else {
                    c0 = (f32x4){bias0, bias0, bias0, bias0};
                    c1 = (f32x4){bias1, bias1, bias1, bias1};
                }
                #pragma unroll
                for (int c = 0; c < KCA; ++c) {
                    const unsigned short *aph, *apl;
                    if (PAIR == 1 && c < 4) {          // x-half = staged h1
                        aph = &sgh[cb][ph][q][32 * c + 8 * g];
                        apl = &sgl[cb][ph][q][32 * c + 8 * g];
                    } else {                            // own h
                        const int cy = (PAIR == 1) ? (c - 4) : c;
                        aph = &hAh[rs][q][32 * cy + 8 * g];
                        apl = &hAl[rs][q][32 * cy + 8 * g];
                    }
                    const bfrag ah = *(const bfrag*)aph;
                    const bfrag al = *(const bfrag*)apl;
                    c0 = MF(ah, bh[0][c], c0);  c1 = MF(ah, bh[1][c], c1);
                    c0 = MF(al, bh[0][c], c0);  c1 = MF(al, bh[1][c], c1);
                    c0 = MF(ah, bl[0][c], c0);  c1 = MF(ah, bl[1][c], c1);
                }
                #pragma unroll
                for (int j = 0; j < 4; ++j) {
                    const int m = 4 * g + j;
                    const float h0 = tanh_fast(c0[j]);
                    const float h1v = tanh_fast(c1[j]);
                    const unsigned u0 = f2bf(h0), u1 = f2bf(h1v);
                    hAh[ws][m][cn0] = (unsigned short)u0;
                    hAh[ws][m][cn1] = (unsigned short)u1;
                    hAl[ws][m][cn0] = (unsigned short)f2bf(h0 - bf2f(u0));
                    hAl[ws][m][cn1] = (unsigned short)f2bf(h1v - bf2f(u1));
                }
            }
        } else {
            // ---- layer B computes h_B(T-1): x = h_A(T-1) slot T^1,
            //      own y = h_B(T-2) slot T, writes slot T^1 ----
            if (T >= 1) {
                const int ys = T & 1, xs = (T ^ 1) & 1, ws = (T ^ 1) & 1;
                f32x4 c0 = (f32x4){bias0, bias0, bias0, bias0};
                f32x4 c1 = (f32x4){bias1, bias1, bias1, bias1};
                #pragma unroll
                for (int c = 0; c < 8; ++c) {
                    const unsigned short *aph, *apl;
                    if (c < 4) {
                        aph = &hAh[xs][q][32 * c + 8 * g];
                        apl = &hAl[xs][q][32 * c + 8 * g];
                    } else {
                        aph = &hBh[ys][q][32 * (c - 4) + 8 * g];
                        apl = &hBl[ys][q][32 * (c - 4) + 8 * g];
                    }
                    const bfrag ah = *(const bfrag*)aph;
                    const bfrag al = *(const bfrag*)apl;
                    c0 = MF(ah, bh[0][c], c0);  c1 = MF(ah, bh[1][c], c1);
                    c0 = MF(al, bh[0][c], c0);  c1 = MF(al, bh[1][c], c1);
                    c0 = MF(ah, bl[0][c], c0);  c1 = MF(ah, bl[1][c], c1);
                }
                #pragma unroll
                for (int j = 0; j < 4; ++j) {
                    const int m = 4 * g + j;
                    const float h0 = tanh_fast(c0[j]);
                    const float h1v = tanh_fast(c1[j]);
                    const unsigned u0 = f2bf(h0), u1 = f2bf(h1v);
                    const unsigned v0 = f2bf(h0 - bf2f(u0)), v1 = f2bf(h1v - bf2f(u1));
                    hBh[ws][m][cn0] = (unsigned short)u0;
                    hBh[ws][m][cn1] = (unsigned short)u1;
                    hBl[ws][m][cn0] = (unsigned short)v0;
                    hBl[ws][m][cn1] = (unsigned short)v1;
                    if (PAIR == 0) {   // persist split h1 for dispatch 2
                        const size_t go = ((size_t)(b0 + m) * SS + (T - 1)) * HH;
                        dst_hi[go + cn0] = (unsigned short)u0;
                        dst_hi[go + cn1] = (unsigned short)u1;
                        dst_lo[go + cn0] = (unsigned short)v0;
                        dst_lo[go + cn1] = (unsigned short)v1;
                    } else if (T == SS) {   // h3(255) -> hfin, full fp32
                        hfin[(size_t)(b0 + m) * HH + cn0] = h0;
                        hfin[(size_t)(b0 + m) * HH + cn1] = h1v;
                    }
                }
            }
        }

        // staging LDS write (into slot cb^1, consumed from T+2 onward)
        if (ph == 2 && T + 2 < SS) {
            *(uint4*)(dp0 + (cb ^ 1) * SGSLOT) = p0;
            *(uint4*)(dp1 + (cb ^ 1) * SGSLOT) = p1;
            *(uint4*)(dp2 + (cb ^ 1) * SGSLOT) = p2;
            *(uint4*)(dp3 + (cb ^ 1) * SGSLOT) = p3;
        }
        barrier_nodrain();
    }
}

// =====================================================================
__global__ __launch_bounds__(128)
void fc_k(const float* __restrict__ hlast, const float* __restrict__ fc_w,
          const float* __restrict__ fc_b, float* __restrict__ out)
{
    const int b = blockIdx.x;
    const int tid = threadIdx.x;
    __shared__ __align__(16) float h[HH];
    h[tid] = hlast[(size_t)b * HH + tid];
    __syncthreads();
    if (tid < NC) {
        float a = fc_b[tid];
        const float* wr = fc_w + tid * HH;
        #pragma unroll 4
        for (int k = 0; k < HH; ++k) a += h[k] * wr[k];
        out[(size_t)b * NC + tid] = a;
    }
}

extern "C" void kernel_launch(void* const* d_in, const int* in_sizes, int n_in,
                              void* d_out, int out_size, void* d_ws, size_t ws_size,
                              hipStream_t stream) {
    const float* x     = (const float*)d_in[0];   // (512,256,28)
    const float* w_ih0 = (const float*)d_in[1];   // (128,28)
    const float* w_hh0 = (const float*)d_in[2];   // (128,128)
    const float* b_ih0 = (const float*)d_in[3];
    const float* b_hh0 = (const float*)d_in[4];
    const float* w_ih  = (const float*)d_in[5];   // (3,128,128): feeds layers 1..3
    const float* w_hh  = (const float*)d_in[6];   // (3,128,128): layers 1..3
    const float* b_ih  = (const float*)d_in[7];   // (3,128)
    const float* b_hh  = (const float*)d_in[8];
    const float* fc_w  = (const float*)d_in[9];   // (10,128)
    const float* fc_b  = (const float*)d_in[10];
    float* out = (float*)d_out;

    // workspace: split-bf16 xw0/h1 buffers (32 MB each) + fp32 hfin
    unsigned short* bufh = (unsigned short*)d_ws;
    unsigned short* bufl = bufh + (size_t)BB * SS * HH;
    float* hfin = (float*)(bufl + (size_t)BB * SS * HH);

    // layer 0 input projection (bias-free, split-bf16 output)
    proj_k<28><<<(BB * SS) / 64, 256, 0, stream>>>(x, w_ih0, bufh, bufl);
    // layers 0+1 (MFMA): layer1 writes split h1 back into buf (in-place)
    scan_mfma<0><<<BB / 16, 512, 0, stream>>>(
        bufh, bufl, bufh, bufl, hfin,
        w_hh0, nullptr,                                   // layer0: K=128 (y only)
        w_ih, w_hh,                                       // layer1: W_ih1, W_hh1
        b_ih0, b_hh0, b_ih, b_hh);
    // layers 2+3 (MFMA): x-half = staged h1; layer3 writes hfin
    scan_mfma<1><<<BB / 16, 512, 0, stream>>>(
        bufh, bufl, nullptr, nullptr, hfin,
        w_ih + (size_t)1 * HH * HH, w_hh + (size_t)1 * HH * HH,   // layer2
        w_ih + (size_t)2 * HH * HH, w_hh + (size_t)2 * HH * HH,   // layer3
        b_ih + HH, b_hh + HH, b_ih + 2 * HH, b_hh + 2 * HH);
    fc_k<<<BB, 128, 0, stream>>>(hfin, fc_w, fc_b, out);
}

// Round 10
// 569.936 us; speedup vs baseline: 1.4265x; 1.4265x over previous
//
#include <hip/hip_runtime.h>

#define BB 512
#define SS 256
#define HH 128
#define NC 10

typedef float v2f __attribute__((ext_vector_type(2)));

// v_pk_fma_f32 is FULL-RATE on gfx950 (R8 arithmetic: 128 copies*2cy +
// 136 pk*X = R7's 272*2cy  =>  X~2cy). Forced via asm; "v" constraints
// require arch-VGPR operands.
__device__ __forceinline__ v2f pkmul(v2f a, v2f b) {
    v2f d;
    asm("v_pk_mul_f32 %0, %1, %2" : "=v"(d) : "v"(a), "v"(b));
    return d;
}
__device__ __forceinline__ v2f pkfma(v2f a, v2f b, v2f c) {
    v2f d;
    asm("v_pk_fma_f32 %0, %1, %2, %3" : "=v"(d) : "v"(a), "v"(b), "v"(c));
    return d;
}

// acc + (give from lane selected by DPP ctrl)
template<int CTRL>
__device__ __forceinline__ float dppadd(float acc, float give) {
    int t = __builtin_amdgcn_update_dpp(0, __float_as_int(give), CTRL, 0xF, 0xF, true);
    return acc + __int_as_float(t);
}

// cndmask-free reduce-scatter over the 16-lane group (verified).
__device__ __forceinline__ float red_scatter(const float v[8], int r) {
    float s0 = dppadd<0xB1>(v[0], v[1]);    // xor1
    float s2 = dppadd<0xB1>(v[2], v[3]);
    float s4 = dppadd<0xB1>(v[4], v[5]);
    float s6 = dppadd<0xB1>(v[6], v[7]);
    s0 = dppadd<0x4E>(s0, s2);              // xor2
    s4 = dppadd<0x4E>(s4, s6);
    {   // xor4 via row_ror 4 / 12
        int t1 = __builtin_amdgcn_update_dpp(0, __float_as_int(s4), 0x124, 0xF, 0xF, true);
        int t2 = __builtin_amdgcn_update_dpp(0, __float_as_int(s4), 0x12C, 0xF, 0xF, true);
        s0 += __int_as_float((r & 4) ? t2 : t1);
    }
    s0 = dppadd<0x128>(s0, s0);             // xor8 (row_ror:8)
    return s0;
}

// Barrier without the compiler's vmcnt(0) drain (LDS-visibility only).
__device__ __forceinline__ void barrier_nodrain() {
    asm volatile("s_waitcnt lgkmcnt(0)\n\ts_barrier" ::: "memory");
}

__device__ __forceinline__ float tanh_fast(float z) {
    const float e = __expf(2.f * z);
    return 1.f - 2.f * __builtin_amdgcn_rcpf(1.f + e);
}

// ---- named weight registers (NOT an array: arrays trigger the AGPR
// promotion heuristic that forced a v_accvgpr_read per use in R7/R8).
// Pinned to arch VGPRs at def with an empty "+v" asm. ----
#define WDECL(i) v2f w##i##_0, w##i##_1, w##i##_2, w##i##_3, \
                     w##i##_4, w##i##_5, w##i##_6, w##i##_7;
#define WLOADX(i) { const v2f* p_ = (const v2f*)(wa + (size_t)(8 * j + ((i) ^ g7)) * HH + 8 * r); \
    w##i##_0 = p_[0]; w##i##_1 = p_[1]; w##i##_2 = p_[2]; w##i##_3 = p_[3];                       \
    asm("" : "+v"(w##i##_0), "+v"(w##i##_1), "+v"(w##i##_2), "+v"(w##i##_3)); }
#define WLOADY(i) { const v2f* p_ = (const v2f*)(wb + (size_t)(8 * j + ((i) ^ g7)) * HH + 8 * r); \
    w##i##_4 = p_[0]; w##i##_5 = p_[1]; w##i##_6 = p_[2]; w##i##_7 = p_[3];                       \
    asm("" : "+v"(w##i##_4), "+v"(w##i##_5), "+v"(w##i##_6), "+v"(w##i##_7)); }
// K=128 MAC slot (x-half only)
#define MAC4(i, x0, x1, x2, x3, d) { v2f a_ = pkmul(x0, w##i##_0);       \
    a_ = pkfma(x1, w##i##_1, a_); a_ = pkfma(x2, w##i##_2, a_);          \
    a_ = pkfma(x3, w##i##_3, a_); d = a_.x + a_.y; }
// K=256 MAC slot (x-half + y-half)
#define MAC8(i, x0, x1, x2, x3, y0, y1, y2, y3, d) { v2f a_ = pkmul(x0, w##i##_0); \
    a_ = pkfma(x1, w##i##_1, a_); a_ = pkfma(x2, w##i##_2, a_);                    \
    a_ = pkfma(x3, w##i##_3, a_); a_ = pkfma(y0, w##i##_4, a_);                    \
    a_ = pkfma(y1, w##i##_5, a_); a_ = pkfma(y2, w##i##_6, a_);                    \
    a_ = pkfma(y3, w##i##_7, a_); d = a_.x + a_.y; }
#define FORSLOT(M) M(0) M(1) M(2) M(3) M(4) M(5) M(6) M(7)

// =====================================================================
// proj_k: out[m][j] = sum_d A[m][d] * W[j][d]   (NO bias — scans add it)
// Layer 0 input projection only (K=28).  (Proven kernel, unchanged.)
// =====================================================================
template<int K>
__global__ __launch_bounds__(256, 1)
void proj_k(const float* __restrict__ A, const float* __restrict__ W,
            float* __restrict__ out)
{
    constexpr int AS = ((K + 31) / 32) * 32 + 4;
    constexpr int KQ = K / 4;
    constexpr int KCW = (K < 32) ? K : 32;
    constexpr int WQ = KCW / 4;
    const int tid = threadIdx.x;
    const int tx = tid & 15;
    const int ty = tid >> 4;
    const size_t m0 = (size_t)blockIdx.x * 64;

    __shared__ float Arm[64 * AS];
    __shared__ float Wst[128 * 36];

    for (int idx = tid; idx < 64 * KQ; idx += 256) {
        const int row = idx / KQ, kq = idx % KQ;
        const float4 v = *(const float4*)(A + (m0 + row) * K + 4 * kq);
        *(float4*)(&Arm[row * AS + 4 * kq]) = v;
    }

    float acc[4][8];
    #pragma unroll
    for (int c = 0; c < 8; ++c)
        #pragma unroll
        for (int r = 0; r < 4; ++r) acc[r][c] = 0.f;

    #pragma unroll 1
    for (int kc = 0; kc < K; kc += KCW) {
        __syncthreads();
        for (int idx = tid; idx < 128 * WQ; idx += 256) {
            const int col = idx / WQ, q = idx % WQ;
            const float4 v = *(const float4*)(W + (size_t)col * K + kc + 4 * q);
            *(float4*)(&Wst[col * 36 + 4 * q]) = v;
        }
        __syncthreads();
        #pragma unroll 2
        for (int q = 0; q < WQ; ++q) {
            float4 av[4];
            #pragma unroll
            for (int r = 0; r < 4; ++r)
                av[r] = *(const float4*)(&Arm[(ty + 16 * r) * AS + kc + 4 * q]);
            #pragma unroll
            for (int c = 0; c < 8; ++c) {
                const float4 wv = *(const float4*)(&Wst[(tx + 16 * c) * 36 + 4 * q]);
                #pragma unroll
                for (int r = 0; r < 4; ++r)
                    acc[r][c] += av[r].x * wv.x + av[r].y * wv.y
                               + av[r].z * wv.z + av[r].w * wv.w;
            }
        }
    }

    #pragma unroll
    for (int r = 0; r < 4; ++r)
        #pragma unroll
        for (int c = 0; c < 8; ++c)
            out[(m0 + ty + 16 * r) * HH + tx + 16 * c] = acc[r][c];
}

// =====================================================================
// scan_fuse<PAIR> (R10 = R7 structure + VGPR-resident pk-FMA MACs):
// TWO stacked layers via combined-K recurrence, 2 batches per block,
// 512 threads = role0 (layer 2*PAIR) + role1 (layer 2*PAIR+1).
//   PAIR=0: role0 = layer0 (staged xw0 + K=128 W_hh0);
//           role1 = layer1 (K=256), writes h1 rows to buf (plain fp32).
//   PAIR=1: role0 = layer2 (K=256, x-half = STAGED h1 rows);
//           role1 = layer3 (K=256), final h -> hfin.
// In-place: row X stage-read at T=X-8, h1-written at T=X+1.
// =====================================================================
template<int PAIR>
__global__ __attribute__((amdgpu_flat_work_group_size(512, 512),
                          amdgpu_waves_per_eu(2, 2)))
void scan_fuse(float* __restrict__ buf, float* __restrict__ hfin,
               const float* __restrict__ w_r0_a, const float* __restrict__ w_r0_b,
               const float* __restrict__ w_r1_a, const float* __restrict__ w_r1_b,
               const float* __restrict__ b0_ih, const float* __restrict__ b0_hh,
               const float* __restrict__ b1_ih, const float* __restrict__ b1_hh)
{
    const int blk  = blockIdx.x;
    const int tid  = threadIdx.x;
    const int role = tid >> 8;       // 0 = layer A, 1 = layer B (combined-K)
    const int t256 = tid & 255;
    const int j   = t256 >> 4;       // col group: cols 8j..8j+7
    const int r   = t256 & 15;       // k-chunk [8r, 8r+8)
    const int g7  = r & 7;
    const int cc  = 8 * j + g7;      // column this lane finalizes
    const int wsw = 12 * j + g7;     // swizzled word for cc

    float* const rowA = buf + (size_t)(2 * blk) * SS * HH;
    float* const rowB = rowA + (size_t)SS * HH;
    const float bias = role ? (b1_ih[cc] + b1_hh[cc]) : (b0_ih[cc] + b0_hh[cc]);

    // permuted weights: slot i = column 8j + (i^g7); _0.._3 = x-half
    // (W_ih or W_hh0), _4.._7 = y-half (W_hh) for combined-K roles.
    const float* wa = role ? w_r1_a : w_r0_a;
    const float* wb = role ? w_r1_b : w_r0_b;
    FORSLOT(WDECL)
    FORSLOT(WLOADX)
    if (PAIR == 1 || role == 1) { FORSLOT(WLOADY) }

    __shared__ float hsw[2][2][2][192];   // [layer][batch][dbuf][192], swizzled
    __shared__ float stg[2][8][2][192];   // [chunk][step][batch][192], swizzled

    for (int i = tid; i < 2 * 2 * 2 * 192; i += 512) ((float*)hsw)[i] = 0.f;

    const int st  = t256 >> 5;            // staging: step-in-chunk
    const int m32 = t256 & 31;            // staging: float4 index in row
    const int spw = 12 * (m32 >> 1) + 4 * (m32 & 1);  // swizzled float4 word
    if (role == 0) {                      // stage rows 0..7 (xw0 or h1)
        const float4 vA = *(const float4*)(rowA + (size_t)st * HH + 4 * m32);
        const float4 vB = *(const float4*)(rowB + (size_t)st * HH + 4 * m32);
        *(float4*)(&stg[0][st][0][spw]) = vA;
        *(float4*)(&stg[0][st][1][spw]) = vB;
    }
    __syncthreads();

    for (int T = 0; T <= SS; ++T) {
        const int cur = T & 1;

        if (role == 0) {
            if (T < SS) {
                const int ph = T & 7, cb = (T >> 3) & 1;
                if ((T & 7) == 0 && T + 8 < SS) {
                    const float4 vA = *(const float4*)(rowA + (size_t)(T + 8 + st) * HH + 4 * m32);
                    const float4 vB = *(const float4*)(rowB + (size_t)(T + 8 + st) * HH + 4 * m32);
                    *(float4*)(&stg[cb ^ 1][st][0][spw]) = vA;
                    *(float4*)(&stg[cb ^ 1][st][1][spw]) = vB;
                }
                // own-h fragments, both batches
                const v2f* hbA = (const v2f*)&hsw[0][0][cur][12 * r];
                const v2f* hbB = (const v2f*)&hsw[0][1][cur][12 * r];
                const v2f yA0 = hbA[0], yA1 = hbA[1], yA2 = hbA[2], yA3 = hbA[3];
                const v2f yB0 = hbB[0], yB1 = hbB[1], yB2 = hbB[2], yB3 = hbB[3];
                float vA[8], vB[8], zA, zB;
                if (PAIR == 0) {
                    #define M0(i) MAC4(i, yA0, yA1, yA2, yA3, vA[i]) \
                                  MAC4(i, yB0, yB1, yB2, yB3, vB[i])
                    FORSLOT(M0)
                    #undef M0
                    zA = stg[cb][ph][0][wsw] + bias + red_scatter(vA, r);
                    zB = stg[cb][ph][1][wsw] + bias + red_scatter(vB, r);
                } else {
                    const v2f* sxA = (const v2f*)&stg[cb][ph][0][12 * r];
                    const v2f* sxB = (const v2f*)&stg[cb][ph][1][12 * r];
                    const v2f xA0 = sxA[0], xA1 = sxA[1], xA2 = sxA[2], xA3 = sxA[3];
                    const v2f xB0 = sxB[0], xB1 = sxB[1], xB2 = sxB[2], xB3 = sxB[3];
                    #define M1(i) MAC8(i, xA0, xA1, xA2, xA3, yA0, yA1, yA2, yA3, vA[i]) \
                                  MAC8(i, xB0, xB1, xB2, xB3, yB0, yB1, yB2, yB3, vB[i])
                    FORSLOT(M1)
                    #undef M1
                    zA = bias + red_scatter(vA, r);
                    zB = bias + red_scatter(vB, r);
                }
                const float nA = tanh_fast(zA);
                const float nB = tanh_fast(zB);
                if (r < 8) {
                    hsw[0][0][cur ^ 1][wsw] = nA;
                    hsw[0][1][cur ^ 1][wsw] = nB;
                }
            }
        } else {
            if (T >= 1) {
                const v2f* hxA = (const v2f*)&hsw[0][0][cur][12 * r];
                const v2f* hxB = (const v2f*)&hsw[0][1][cur][12 * r];
                const v2f* hyA = (const v2f*)&hsw[1][0][cur][12 * r];
                const v2f* hyB = (const v2f*)&hsw[1][1][cur][12 * r];
                const v2f xA0 = hxA[0], xA1 = hxA[1], xA2 = hxA[2], xA3 = hxA[3];
                const v2f xB0 = hxB[0], xB1 = hxB[1], xB2 = hxB[2], xB3 = hxB[3];
                const v2f yA0 = hyA[0], yA1 = hyA[1], yA2 = hyA[2], yA3 = hyA[3];
                const v2f yB0 = hyB[0], yB1 = hyB[1], yB2 = hyB[2], yB3 = hyB[3];
                float vA[8], vB[8];
                #define M2(i) MAC8(i, xA0, xA1, xA2, xA3, yA0, yA1, yA2, yA3, vA[i]) \
                              MAC8(i, xB0, xB1, xB2, xB3, yB0, yB1, yB2, yB3, vB[i])
                FORSLOT(M2)
                #undef M2
                const float zA = bias + red_scatter(vA, r);
                const float zB = bias + red_scatter(vB, r);
                const float nA = tanh_fast(zA);
                const float nB = tanh_fast(zB);
                if (r < 8) {
                    hsw[1][0][cur ^ 1][wsw] = nA;
                    hsw[1][1][cur ^ 1][wsw] = nB;
                    if (PAIR == 0) {   // persist h1 for dispatch 2
                        rowA[(size_t)(T - 1) * HH + cc] = nA;
                        rowB[(size_t)(T - 1) * HH + cc] = nB;
                    }
                }
            }
        }
        barrier_nodrain();
    }

    // PAIR=1: h3(SS-1) written at T=SS into dbuf[1]
    if (PAIR == 1 && role == 1) {
        if (t256 < 32) {
            const float4 hv = *(const float4*)(&hsw[1][0][1][12 * (t256 >> 1) + 4 * (t256 & 1)]);
            *(float4*)(hfin + (size_t)(2 * blk) * HH + 4 * t256) = hv;
        } else if (t256 < 64) {
            const int t2 = t256 - 32;
            const float4 hv = *(const float4*)(&hsw[1][1][1][12 * (t2 >> 1) + 4 * (t2 & 1)]);
            *(float4*)(hfin + (size_t)(2 * blk + 1) * HH + 4 * t2) = hv;
        }
    }
}

// =====================================================================
__global__ __launch_bounds__(128)
void fc_k(const float* __restrict__ hlast, const float* __restrict__ fc_w,
          const float* __restrict__ fc_b, float* __restrict__ out)
{
    const int b = blockIdx.x;
    const int tid = threadIdx.x;
    __shared__ __align__(16) float h[HH];
    h[tid] = hlast[(size_t)b * HH + tid];
    __syncthreads();
    if (tid < NC) {
        float a = fc_b[tid];
        const float* wr = fc_w + tid * HH;
        #pragma unroll 4
        for (int k = 0; k < HH; ++k) a += h[k] * wr[k];
        out[(size_t)b * NC + tid] = a;
    }
}

extern "C" void kernel_launch(void* const* d_in, const int* in_sizes, int n_in,
                              void* d_out, int out_size, void* d_ws, size_t ws_size,
                              hipStream_t stream) {
    const float* x     = (const float*)d_in[0];   // (512,256,28)
    const float* w_ih0 = (const float*)d_in[1];   // (128,28)
    const float* w_hh0 = (const float*)d_in[2];   // (128,128)
    const float* b_ih0 = (const float*)d_in[3];
    const float* b_hh0 = (const float*)d_in[4];
    const float* w_ih  = (const float*)d_in[5];   // (3,128,128): layers 1..3 input proj
    const float* w_hh  = (const float*)d_in[6];   // (3,128,128): layers 1..3 recurrent
    const float* b_ih  = (const float*)d_in[7];   // (3,128)
    const float* b_hh  = (const float*)d_in[8];
    const float* fc_w  = (const float*)d_in[9];   // (10,128)
    const float* fc_b  = (const float*)d_in[10];
    float* out = (float*)d_out;

    float* buf  = (float*)d_ws;                   // (B,S,H) fp32 = 64 MB
    float* hfin = buf + (size_t)BB * SS * HH;     // (B,H)

    // layer 0 input projection (bias-free; scans add bias)
    proj_k<28><<<(BB * SS) / 64, 256, 0, stream>>>(x, w_ih0, buf);
    // layers 0+1: role0 = layer0 rec (staged xw0), role1 = layer1
    // combined-K (writes h1 rows into buf)
    scan_fuse<0><<<BB / 2, 512, 0, stream>>>(
        buf, hfin,
        w_hh0, nullptr,
        w_ih, w_hh,                                  // layer 1: W_ih1, W_hh1
        b_ih0, b_hh0, b_ih, b_hh);
    // layers 2+3: role0 = layer2 combined-K (x-half = staged h1 rows),
    // role1 = layer3 combined-K (writes final h)
    scan_fuse<1><<<BB / 2, 512, 0, stream>>>(
        buf, hfin,
        w_ih + (size_t)1 * HH * HH, w_hh + (size_t)1 * HH * HH,  // layer 2
        w_ih + (size_t)2 * HH * HH, w_hh + (size_t)2 * HH * HH,  // layer 3
        b_ih + HH, b_hh + HH, b_ih + 2 * HH, b_hh + 2 * HH);
    fc_k<<<BB, 128, 0, stream>>>(hfin, fc_w, fc_b, out);
}